// Round 8
// baseline (133.624 us; speedup 1.0000x reference)
//
#include <hip/hip_runtime.h>
#include <hip/hip_bf16.h>

typedef __attribute__((ext_vector_type(8))) short bf16x8;
typedef __attribute__((ext_vector_type(4))) float f32x4;

#define NB 4096
#define ND 512
#define MARGIN_F 0.2f

// order-preserving float -> uint encoding for atomicMax.
// enc(f) == 0 impossible for finite f => rowmax[a]==0 <=> has_neg==false.
__device__ __forceinline__ unsigned int enc_f32(float f) {
    unsigned int b = __float_as_uint(f);
    return (b & 0x80000000u) ? ~b : (b | 0x80000000u);
}

__device__ __forceinline__ float dec_f32(unsigned int e) {
    unsigned int b = (e & 0x80000000u) ? (e & 0x7fffffffu) : ~e;
    return __uint_as_float(b);
}

__device__ __forceinline__ void gld_lds16(const void* g, void* l) {
    __builtin_amdgcn_global_load_lds((__attribute__((address_space(1))) void*)g,
                                     (__attribute__((address_space(3))) void*)l,
                                     16, 0, 0);
}

// ---------------------------------------------------------------------------
// Prep: fp32 -> bf16 fragment-swizzled convert (both matrices), grid 2048.
// Blocks [0,16) zero the 4096-entry rowmax array.
// Swizzle: subtile = 16 rows x 32 cols; si = (row/16)*16 + (col/32);
// lane = (row%16) | (((col%32)/8)<<4); flat = si*512 + lane*8 + j.
// ---------------------------------------------------------------------------
__global__ __launch_bounds__(256) void k_prep(const float* __restrict__ zs,
                                              const float* __restrict__ zi,
                                              __hip_bfloat16* __restrict__ outb,
                                              unsigned int* __restrict__ rowmax) {
    const int bid = blockIdx.x;
    if (bid < 16) rowmax[bid * 256 + threadIdx.x] = 0u;

    int gid = bid * 256 + threadIdx.x;   // [0, 2*4096*64)
    int mat = gid >> 18;                 // 0 = zs, 1 = zi
    int t   = gid & 0x3FFFF;
    int si  = t >> 6;
    int L   = t & 63;
    const float* src = mat ? zi : zs;
    int row = ((si >> 4) << 4) | (L & 15);
    int col = ((si & 15) << 5) | (((L >> 4) & 3) << 3);
    const float4* p = (const float4*)(src + (size_t)row * ND + col);
    float4 f0 = p[0];
    float4 f1 = p[1];
    union { __hip_bfloat16 h[8]; bf16x8 v; } u;
    u.h[0] = __float2bfloat16(f0.x);
    u.h[1] = __float2bfloat16(f0.y);
    u.h[2] = __float2bfloat16(f0.z);
    u.h[3] = __float2bfloat16(f0.w);
    u.h[4] = __float2bfloat16(f1.x);
    u.h[5] = __float2bfloat16(f1.y);
    u.h[6] = __float2bfloat16(f1.z);
    u.h[7] = __float2bfloat16(f1.w);
    bf16x8* dst = (bf16x8*)(outb + ((size_t)mat << 21) + ((size_t)si << 9) + (L << 3));
    *dst = u.v;
}

// ---------------------------------------------------------------------------
// 128x128 tile GEMM (S = Zs . Zi^T), BK=64, 4 waves, wave tile 64x64 as
// 4x4 of 16x16x32 bf16 MFMA. Epilogue: per-row different-label max ->
// atomicMax; diagonal blocks extract p_diag[a] = 1 - S[a][a].
// R8: launched TWICE (idempotent) to measure its true duration as the
// delta vs R3's 104.1 us — it has never been directly visible in top-5.
// ---------------------------------------------------------------------------
__global__ __launch_bounds__(256) void k_gemm_rowmax(const __hip_bfloat16* __restrict__ zsb,
                                                     const __hip_bfloat16* __restrict__ zib,
                                                     const int* __restrict__ labels,
                                                     unsigned int* __restrict__ rowmax,
                                                     float* __restrict__ p_diag) {
    __shared__ __align__(16) unsigned char sA[16384];   // 8 row-sub x 2 k-sub x 1KB
    __shared__ __align__(16) unsigned char sB[16384];
    __shared__ int labA[128];
    __shared__ int labB[128];

    const int tid = threadIdx.x;
    const int bx = blockIdx.x, by = blockIdx.y;

    if (tid < 128) labA[tid] = labels[by * 128 + tid];
    else           labB[tid - 128] = labels[bx * 128 + (tid - 128)];

    const char* gA = (const char*)zsb;
    const char* gB = (const char*)zib;
    const int rb0 = tid >> 7;              // 0/1
    const int rem = (tid & 127) << 4;      // covers kb*1024 + lane*16
    size_t aStat[4], bStat[4];
#pragma unroll
    for (int rd = 0; rd < 4; ++rd) {
        int rb = rd * 2 + rb0;             // local row-block 0..7
        aStat[rd] = ((size_t)(by * 8 + rb) << 14) + rem;   // *16384 bytes
        bStat[rd] = ((size_t)(bx * 8 + rb) << 14) + rem;
    }

    const int w = tid >> 6, lane = tid & 63;
    const int w_m = w >> 1, w_n = w & 1;
    const int fragOff = lane << 4;

    f32x4 acc[4][4];
#pragma unroll
    for (int i = 0; i < 4; ++i)
#pragma unroll
        for (int j = 0; j < 4; ++j)
            acc[i][j] = (f32x4){0.f, 0.f, 0.f, 0.f};

    for (int ks = 0; ks < 8; ++ks) {
        __syncthreads();
#pragma unroll
        for (int rd = 0; rd < 4; ++rd) {
            gld_lds16(gA + aStat[rd] + (size_t)ks * 2048, sA + rd * 4096 + (tid << 4));
            gld_lds16(gB + bStat[rd] + (size_t)ks * 2048, sB + rd * 4096 + (tid << 4));
        }
        __syncthreads();
#pragma unroll
        for (int kb = 0; kb < 2; ++kb) {
            bf16x8 af[4], bfr[4];
#pragma unroll
            for (int ms = 0; ms < 4; ++ms)
                af[ms] = *(const bf16x8*)(sA + (((w_m * 4 + ms) * 2 + kb) << 10) + fragOff);
#pragma unroll
            for (int ns = 0; ns < 4; ++ns)
                bfr[ns] = *(const bf16x8*)(sB + (((w_n * 4 + ns) * 2 + kb) << 10) + fragOff);
#pragma unroll
            for (int ms = 0; ms < 4; ++ms)
#pragma unroll
                for (int ns = 0; ns < 4; ++ns)
                    acc[ms][ns] = __builtin_amdgcn_mfma_f32_16x16x32_bf16(
                        af[ms], bfr[ns], acc[ms][ns], 0, 0, 0);
        }
    }

    // epilogue: C/D layout col = lane&15, row = (lane>>4)*4 + reg
    const int quad = lane >> 4;
    const int lcol = lane & 15;

    int lb[4];
#pragma unroll
    for (int ns = 0; ns < 4; ++ns)
        lb[ns] = labB[w_n * 64 + ns * 16 + lcol];

#pragma unroll
    for (int ms = 0; ms < 4; ++ms) {
        int la[4];
#pragma unroll
        for (int r = 0; r < 4; ++r)
            la[r] = labA[w_m * 64 + ms * 16 + quad * 4 + r];
        float mx[4] = {-3.0e38f, -3.0e38f, -3.0e38f, -3.0e38f};
#pragma unroll
        for (int ns = 0; ns < 4; ++ns) {
#pragma unroll
            for (int r = 0; r < 4; ++r) {
                float v = acc[ms][ns][r];
                if (la[r] != lb[ns] && v > mx[r]) mx[r] = v;
            }
        }
#pragma unroll
        for (int r = 0; r < 4; ++r) {
            float m = mx[r];
            m = fmaxf(m, __shfl_xor(m, 1));
            m = fmaxf(m, __shfl_xor(m, 2));
            m = fmaxf(m, __shfl_xor(m, 4));
            m = fmaxf(m, __shfl_xor(m, 8));
            if (lcol == 0 && m > -2.9e38f) {
                int rowg = by * 128 + w_m * 64 + ms * 16 + quad * 4 + r;
                atomicMax(&rowmax[rowg], enc_f32(m));
            }
        }
    }

    // diagonal blocks: extract p[a] = 1 - S[a][a]
    if (bx == by && w_m == w_n) {
        int r = lcol - quad * 4;
        if (r >= 0 && r < 4) {
#pragma unroll
            for (int ms = 0; ms < 4; ++ms) {
                int rowg = by * 128 + w_m * 64 + ms * 16 + lcol;
                p_diag[rowg] = 1.0f - acc[ms][ms][r];
            }
        }
    }
}

// ---------------------------------------------------------------------------
// Finalize: has_neg = (rowmax != 0); n = 1 - dec(rowmax);
// per = relu(p - n + margin); masked mean -> out[0]
// ---------------------------------------------------------------------------
__global__ __launch_bounds__(1024) void k_finalize(const unsigned int* __restrict__ rowmax,
                                                   const float* __restrict__ p_diag,
                                                   float* __restrict__ out) {
    int tid = threadIdx.x;
    float sum = 0.0f;
    int cnt = 0;
#pragma unroll
    for (int it = 0; it < 4; ++it) {
        int a = tid + it * 1024;
        unsigned int e = rowmax[a];
        if (e != 0u) {
            float n = 1.0f - dec_f32(e);
            float per = p_diag[a] - n + MARGIN_F;
            if (per > 0.0f) sum += per;
            cnt++;
        }
    }
#pragma unroll
    for (int off = 32; off > 0; off >>= 1) {
        sum += __shfl_xor(sum, off);
        cnt += __shfl_xor(cnt, off);
    }
    __shared__ float sSum[16];
    __shared__ int sCnt[16];
    int w = tid >> 6, lane = tid & 63;
    if (lane == 0) { sSum[w] = sum; sCnt[w] = cnt; }
    __syncthreads();
    if (tid == 0) {
        float ts = 0.0f;
        int tc = 0;
#pragma unroll
        for (int i = 0; i < 16; ++i) { ts += sSum[i]; tc += sCnt[i]; }
        out[0] = (tc > 0) ? ts / (float)tc : 0.0f;
    }
}

extern "C" void kernel_launch(void* const* d_in, const int* in_sizes, int n_in,
                              void* d_out, int out_size, void* d_ws, size_t ws_size,
                              hipStream_t stream) {
    (void)in_sizes; (void)n_in; (void)out_size; (void)ws_size;
    const float* zs = (const float*)d_in[0];
    const float* zi = (const float*)d_in[1];
    const int* labels = (const int*)d_in[2];
    float* out = (float*)d_out;

    char* ws = (char*)d_ws;
    __hip_bfloat16* zb = (__hip_bfloat16*)ws;                       // 8 MB (zs then zi, swizzled)
    unsigned int* rowmax = (unsigned int*)(ws + (8u << 20));        // 16 KB
    float* p_diag = (float*)(ws + (8u << 20) + 16384);              // 16 KB

    k_prep<<<2048, 256, 0, stream>>>(zs, zi, zb, rowmax);
    dim3 g(32, 32);
    // Launched twice deliberately (idempotent): the dur_us delta vs R3's
    // 104.1 us measures the true GEMM duration, which no profile has shown.
    k_gemm_rowmax<<<g, 256, 0, stream>>>(zb, zb + (size_t)NB * ND, labels, rowmax, p_diag);
    k_gemm_rowmax<<<g, 256, 0, stream>>>(zb, zb + (size_t)NB * ND, labels, rowmax, p_diag);
    k_finalize<<<1, 1024, 0, stream>>>(rowmax, p_diag, out);
}